// Round 3
// baseline (2303.180 us; speedup 1.0000x reference)
//
#include <hip/hip_runtime.h>

// AttentionXL (TransformerXL relative attention), MI355X gfx950.
// I/O dtype: float32 (per reference). Compute: bf16 MFMA GEMMs (fp32 accum),
// bf16 intermediates in ws. Flash kernel still the naive bisection version
// this round (dtype fix is the single variable under test).

typedef unsigned short u16;
typedef short short8 __attribute__((ext_vector_type(8)));
typedef float f32x4 __attribute__((ext_vector_type(4)));

#define CUR 512
#define FULLS 1024
#define BSZ 4
#define NH 16
#define DH 64
#define PREV 512

__device__ __forceinline__ float b2f(u16 u) {
  union { unsigned int i; float f; } x; x.i = ((unsigned int)u) << 16; return x.f;
}
__device__ __forceinline__ u16 f2b(float f) {
  union { float f; unsigned int i; } x; x.f = f;
  unsigned int u = x.i;
  return (u16)((u + 0x7fffu + ((u >> 16) & 1u)) >> 16);
}

// load 8 consecutive elements as bf16 short8, from either fp32 or bf16 memory
__device__ __forceinline__ short8 load8bf(const float* p) {
  const f32x4* q = reinterpret_cast<const f32x4*>(p);
  f32x4 a = q[0], b = q[1];
  short8 r;
#pragma unroll
  for (int e = 0; e < 4; e++) { r[e] = (short)f2b(a[e]); r[e + 4] = (short)f2b(b[e]); }
  return r;
}
__device__ __forceinline__ short8 load8bf(const u16* p) {
  return *reinterpret_cast<const short8*>(p);
}
__device__ __forceinline__ void storeC(u16* C, size_t idx, float v) { C[idx] = f2b(v); }
__device__ __forceinline__ void storeC(float* C, size_t idx, float v) { C[idx] = v; }

// ---------------------------------------------------------------------------
// GEMM: C[M,N] = A[M,K] @ B[K,N] + bias[N].  A: fp32 or bf16; B,bias: fp32;
// C: fp32 or bf16. fp32 MFMA accum. 128x128 tile, BK=64, 4 waves (2x2).
// ---------------------------------------------------------------------------
template <typename AT, typename OT>
__global__ __launch_bounds__(256, 2)
void gemm_any(const AT* __restrict__ A, const float* __restrict__ B,
              const float* __restrict__ bias, OT* __restrict__ C,
              int M, int N, int K)
{
  __shared__ __align__(16) short at[8192];
  __shared__ __align__(16) short bt[8192];

  const int tid = threadIdx.x;
  const int lane = tid & 63, w = tid >> 6;
  const int wr = w >> 1, wc = w & 1;
  const int quad = lane >> 4, ml = lane & 15;
  const int row0 = blockIdx.y * 128, col0 = blockIdx.x * 128;

  f32x4 acc[4][4];
  const f32x4 fzero = {0.f, 0.f, 0.f, 0.f};
#pragma unroll
  for (int i = 0; i < 4; i++)
#pragma unroll
    for (int j = 0; j < 4; j++) acc[i][j] = fzero;

  for (int k0 = 0; k0 < K; k0 += 64) {
    __syncthreads();
    // stage A tile (128 m x 64 k) into A-frag order
#pragma unroll
    for (int cc = 0; cc < 4; cc++) {
      int c = tid + 256 * cc;
      int m = c >> 3, oct = c & 7;
      short8 val = load8bf(A + (size_t)(row0 + m) * K + k0 + oct * 8);
      int mc = m >> 4, mll = m & 15, kc = oct >> 2, qd = oct & 3;
      *reinterpret_cast<short8*>(at + (((mc * 2 + kc) * 64) + qd * 16 + mll) * 8) = val;
    }
    // stage B tile (64 k x 128 n) transposed into B-frag order
#pragma unroll
    for (int cc = 0; cc < 4; cc++) {
      int c = tid + 256 * cc;
      int k = c >> 4, noct = c & 15;
      short8 val = load8bf(B + (size_t)(k0 + k) * N + col0 + noct * 8);
      int kc = k >> 5, qd = (k >> 3) & 3, jj = k & 7;
#pragma unroll
      for (int e = 0; e < 8; e++) {
        int n = noct * 8 + e;
        int nc = n >> 4, nl = n & 15;
        bt[(((nc * 2 + kc) * 64) + qd * 16 + nl) * 8 + jj] = val[e];
      }
    }
    __syncthreads();

    short8 af[4][2], bf[4][2];
#pragma unroll
    for (int mc = 0; mc < 4; mc++)
#pragma unroll
      for (int kc = 0; kc < 2; kc++)
        af[mc][kc] = *reinterpret_cast<const short8*>(at + ((((wr * 4 + mc) * 2 + kc) * 64) + lane) * 8);
#pragma unroll
    for (int nc = 0; nc < 4; nc++)
#pragma unroll
      for (int kc = 0; kc < 2; kc++)
        bf[nc][kc] = *reinterpret_cast<const short8*>(bt + ((((wc * 4 + nc) * 2 + kc) * 64) + lane) * 8);

#pragma unroll
    for (int mc = 0; mc < 4; mc++)
#pragma unroll
      for (int nc = 0; nc < 4; nc++)
#pragma unroll
        for (int kc = 0; kc < 2; kc++)
          acc[mc][nc] = __builtin_amdgcn_mfma_f32_16x16x32_bf16(af[mc][kc], bf[nc][kc], acc[mc][nc], 0, 0, 0);
  }

#pragma unroll
  for (int nc = 0; nc < 4; nc++) {
    int col = col0 + wc * 64 + nc * 16 + ml;
    float bv = bias[col];
#pragma unroll
    for (int mc = 0; mc < 4; mc++) {
#pragma unroll
      for (int reg = 0; reg < 4; reg++) {
        int row = row0 + wr * 64 + mc * 16 + quad * 4 + reg;
        storeC(C, (size_t)row * N + col, acc[mc][nc][reg] + bv);
      }
    }
  }
}

// ---------------------------------------------------------------------------
// NAIVE flash attention: one wave per (i, b, h); lane = d.
// q/kv/r are bf16 (ws); u/v are fp32 (inputs). Online softmax in fp32.
// ---------------------------------------------------------------------------
__global__ __launch_bounds__(256, 2)
void flash_naive(const u16* __restrict__ q, const u16* __restrict__ kv,
                 const u16* __restrict__ r, const float* __restrict__ u,
                 const float* __restrict__ v, u16* __restrict__ av)
{
  const int tid = threadIdx.x, lane = tid & 63, w = tid >> 6;
  const int b = blockIdx.y, h = blockIdx.z;
  const int i = blockIdx.x * 4 + w;           // query row, 0..511

  const int d = lane;
  const float qf = b2f(q[((size_t)i * BSZ + b) * 1024 + h * 64 + d]);
  const float qu = qf + u[h * 64 + d];
  const float qv = qf + v[h * 64 + d];

  float m = -1e30f, l = 0.f, o = 0.f;
  const int jmax = i + PREV;                   // inclusive; <= 1023

  for (int j = 0; j <= jmax; j++) {
    const int rel = j - i + 511;               // in [0, 1023]
    float kd = b2f(kv[((size_t)j * BSZ + b) * 2048 + h * 64 + d]);
    float rd = b2f(r[(size_t)rel * 1024 + h * 64 + d]);
    float sd = qu * kd + qv * rd;
#pragma unroll
    for (int off = 32; off > 0; off >>= 1) sd += __shfl_xor(sd, off, 64);
    float s = sd * 0.125f;                     // 1/sqrt(64)
    float mnew = fmaxf(m, s);
    float alpha = __expf(m - mnew);
    float p = __expf(s - mnew);
    float vd = b2f(kv[((size_t)j * BSZ + b) * 2048 + 1024 + h * 64 + d]);
    l = l * alpha + p;
    o = o * alpha + p * vd;
    m = mnew;
  }

  av[((size_t)i * BSZ + b) * 1024 + h * 64 + d] = f2b(o / l);
}

// ---------------------------------------------------------------------------
extern "C" void kernel_launch(void* const* d_in, const int* in_sizes, int n_in,
                              void* d_out, int out_size, void* d_ws, size_t ws_size,
                              hipStream_t stream) {
  (void)in_sizes; (void)n_in; (void)out_size; (void)ws_size;

  const float* inputs  = (const float*)d_in[0];   // (512,4,1024)
  const float* pos_emb = (const float*)d_in[1];   // (1024,1,1024)
  const float* full_in = (const float*)d_in[2];   // (1024,4,1024)
  const float* u       = (const float*)d_in[3];   // (16,64)
  const float* v       = (const float*)d_in[4];   // (16,64)
  const float* W_kv    = (const float*)d_in[5];   // (1024,2048)
  const float* b_kv    = (const float*)d_in[6];   // (2048,)
  const float* W_q     = (const float*)d_in[7];   // (1024,1024)
  const float* b_q     = (const float*)d_in[8];
  const float* W_pos   = (const float*)d_in[9];   // (1024,1024)
  const float* b_pos   = (const float*)d_in[10];
  const float* W_proj  = (const float*)d_in[11];  // (1024,1024)
  const float* b_proj  = (const float*)d_in[12];
  // d_in[13] = mask (bool) — recomputed analytically (j > i + 512)
  float* out = (float*)d_out;

  char* ws = (char*)d_ws;
  u16* kv = (u16*)(ws);                                            // 16 MB
  u16* qq = (u16*)(ws + (16u << 20));                              // 4 MB
  u16* rr = (u16*)(ws + (16u << 20) + (4u << 20));                 // 2 MB
  u16* av = (u16*)(ws + (16u << 20) + (4u << 20) + (2u << 20));    // 4 MB

  hipLaunchKernelGGL((gemm_any<float, u16>), dim3(16, 32), dim3(256), 0, stream,
                     full_in, W_kv, b_kv, kv, 4096, 2048, 1024);
  hipLaunchKernelGGL((gemm_any<float, u16>), dim3(8, 16), dim3(256), 0, stream,
                     inputs, W_q, b_q, qq, 2048, 1024, 1024);
  hipLaunchKernelGGL((gemm_any<float, u16>), dim3(8, 8), dim3(256), 0, stream,
                     pos_emb, W_pos, b_pos, rr, 1024, 1024, 1024);
  hipLaunchKernelGGL(flash_naive, dim3(128, 4, 16), dim3(256), 0, stream,
                     qq, kv, rr, u, v, av);
  hipLaunchKernelGGL((gemm_any<u16, float>), dim3(8, 16), dim3(256), 0, stream,
                     av, W_proj, b_proj, out, 2048, 1024, 1024);
}

// Round 4
// 449.558 us; speedup vs baseline: 5.1232x; 5.1232x over previous
//
#include <hip/hip_runtime.h>

// AttentionXL (TransformerXL relative attention), MI355X gfx950.
// fp32 I/O, bf16 MFMA compute (fp32 accum), bf16 intermediates in ws.
// This round: naive flash -> MFMA flash (fused QK^T + rel-pos + online
// softmax + PV), GEMMs unchanged.

typedef unsigned short u16;
typedef short short8 __attribute__((ext_vector_type(8)));
typedef float f32x4 __attribute__((ext_vector_type(4)));

#define CUR 512
#define FULLS 1024
#define BSZ 4
#define NH 16
#define DH 64
#define PREV 512

__device__ __forceinline__ float b2f(u16 u) {
  union { unsigned int i; float f; } x; x.i = ((unsigned int)u) << 16; return x.f;
}
__device__ __forceinline__ u16 f2b(float f) {
  union { float f; unsigned int i; } x; x.f = f;
  unsigned int u = x.i;
  return (u16)((u + 0x7fffu + ((u >> 16) & 1u)) >> 16);
}

__device__ __forceinline__ short8 load8bf(const float* p) {
  const f32x4* q = reinterpret_cast<const f32x4*>(p);
  f32x4 a = q[0], b = q[1];
  short8 r;
#pragma unroll
  for (int e = 0; e < 4; e++) { r[e] = (short)f2b(a[e]); r[e + 4] = (short)f2b(b[e]); }
  return r;
}
__device__ __forceinline__ short8 load8bf(const u16* p) {
  return *reinterpret_cast<const short8*>(p);
}
__device__ __forceinline__ void storeC(u16* C, size_t idx, float v) { C[idx] = f2b(v); }
__device__ __forceinline__ void storeC(float* C, size_t idx, float v) { C[idx] = v; }

// ---------------------------------------------------------------------------
// GEMM: C[M,N] = A[M,K] @ B[K,N] + bias[N]. 128x128 tile, BK=64, 4 waves.
// ---------------------------------------------------------------------------
template <typename AT, typename OT>
__global__ __launch_bounds__(256, 2)
void gemm_any(const AT* __restrict__ A, const float* __restrict__ B,
              const float* __restrict__ bias, OT* __restrict__ C,
              int M, int N, int K)
{
  __shared__ __align__(16) short at[8192];
  __shared__ __align__(16) short bt[8192];

  const int tid = threadIdx.x;
  const int lane = tid & 63, w = tid >> 6;
  const int wr = w >> 1, wc = w & 1;
  const int quad = lane >> 4, ml = lane & 15;
  const int row0 = blockIdx.y * 128, col0 = blockIdx.x * 128;

  f32x4 acc[4][4];
  const f32x4 fzero = {0.f, 0.f, 0.f, 0.f};
#pragma unroll
  for (int i = 0; i < 4; i++)
#pragma unroll
    for (int j = 0; j < 4; j++) acc[i][j] = fzero;

  for (int k0 = 0; k0 < K; k0 += 64) {
    __syncthreads();
#pragma unroll
    for (int cc = 0; cc < 4; cc++) {
      int c = tid + 256 * cc;
      int m = c >> 3, oct = c & 7;
      short8 val = load8bf(A + (size_t)(row0 + m) * K + k0 + oct * 8);
      int mc = m >> 4, mll = m & 15, kc = oct >> 2, qd = oct & 3;
      *reinterpret_cast<short8*>(at + (((mc * 2 + kc) * 64) + qd * 16 + mll) * 8) = val;
    }
#pragma unroll
    for (int cc = 0; cc < 4; cc++) {
      int c = tid + 256 * cc;
      int k = c >> 4, noct = c & 15;
      short8 val = load8bf(B + (size_t)(k0 + k) * N + col0 + noct * 8);
      int kc = k >> 5, qd = (k >> 3) & 3, jj = k & 7;
#pragma unroll
      for (int e = 0; e < 8; e++) {
        int n = noct * 8 + e;
        int nc = n >> 4, nl = n & 15;
        bt[(((nc * 2 + kc) * 64) + qd * 16 + nl) * 8 + jj] = val[e];
      }
    }
    __syncthreads();

    short8 af[4][2], bf[4][2];
#pragma unroll
    for (int mc = 0; mc < 4; mc++)
#pragma unroll
      for (int kc = 0; kc < 2; kc++)
        af[mc][kc] = *reinterpret_cast<const short8*>(at + ((((wr * 4 + mc) * 2 + kc) * 64) + lane) * 8);
#pragma unroll
    for (int nc = 0; nc < 4; nc++)
#pragma unroll
      for (int kc = 0; kc < 2; kc++)
        bf[nc][kc] = *reinterpret_cast<const short8*>(bt + ((((wc * 4 + nc) * 2 + kc) * 64) + lane) * 8);

#pragma unroll
    for (int mc = 0; mc < 4; mc++)
#pragma unroll
      for (int nc = 0; nc < 4; nc++)
#pragma unroll
        for (int kc = 0; kc < 2; kc++)
          acc[mc][nc] = __builtin_amdgcn_mfma_f32_16x16x32_bf16(af[mc][kc], bf[nc][kc], acc[mc][nc], 0, 0, 0);
  }

#pragma unroll
  for (int nc = 0; nc < 4; nc++) {
    int col = col0 + wc * 64 + nc * 16 + ml;
    float bv = bias[col];
#pragma unroll
    for (int mc = 0; mc < 4; mc++) {
#pragma unroll
      for (int reg = 0; reg < 4; reg++) {
        int row = row0 + wr * 64 + mc * 16 + quad * 4 + reg;
        storeC(C, (size_t)row * N + col, acc[mc][nc][reg] + bv);
      }
    }
  }
}

// ---------------------------------------------------------------------------
// Fused MFMA flash attention with TransformerXL relative position.
// Block = 256 threads (4 waves); block handles (i-tile of 64, b, h);
// wave w owns rows [i0+16w, i0+16w+15]. Per j-tile of 64: QK^T via MFMA,
// rel term via per-wave pos2[16 x 80] MFMA strip + LDS diagonal gather
// (rel = j - i + 511), online softmax, P->A-frag via per-wave LDS, PV MFMA.
// ---------------------------------------------------------------------------
__global__ __launch_bounds__(256, 2)
void flash_xl(const u16* __restrict__ q, const u16* __restrict__ kv,
              const u16* __restrict__ r, const float* __restrict__ u,
              const float* __restrict__ v, u16* __restrict__ av)
{
  __shared__ __align__(16) short kt[4096];   // K tile, B-frag [(kc*4+nc)][lane][8]
  __shared__ __align__(16) short vt[4096];   // V tile transposed, B-frag (n=d, k=jl)
  __shared__ __align__(16) short rst[8192];  // R strip 128 rel x 64 d, B-frag [(kc*8+nc)][lane][8]
  __shared__ float pos2w[4][16 * 84];        // per-wave pos2 scratch, row stride 84
  __shared__ __align__(16) short pt[4][1024];// per-wave P in A-frag order

  const int tid = threadIdx.x, lane = tid & 63, w = tid >> 6;
  const int quad = lane >> 4, ml = lane & 15;
  const int it = blockIdx.x, b = blockIdx.y, h = blockIdx.z;
  const int i0 = it * 64;

  // Q fragments (A-operand): rows i0 + w*16 + ml, +u (content) / +v (position)
  short8 qu[2], qvf[2];
  {
    int ig = i0 + w * 16 + ml;
#pragma unroll
    for (int kc = 0; kc < 2; kc++) {
      int dbase = kc * 32 + quad * 8;
      short8 qq = *reinterpret_cast<const short8*>(q + ((size_t)ig * BSZ + b) * 1024 + h * 64 + dbase);
      const f32x4* up = reinterpret_cast<const f32x4*>(u + h * 64 + dbase);
      const f32x4* vp = reinterpret_cast<const f32x4*>(v + h * 64 + dbase);
      f32x4 u0 = up[0], u1 = up[1], v0 = vp[0], v1 = vp[1];
#pragma unroll
      for (int e = 0; e < 8; e++) {
        float qf = b2f((u16)qq[e]);
        float uu = (e < 4) ? u0[e] : u1[e - 4];
        float vv = (e < 4) ? v0[e] : v1[e - 4];
        qu[kc][e]  = (short)f2b(qf + uu);
        qvf[kc][e] = (short)f2b(qf + vv);
      }
    }
  }

  const f32x4 fzero = {0.f, 0.f, 0.f, 0.f};
  f32x4 o_acc[4];
#pragma unroll
  for (int i = 0; i < 4; i++) o_acc[i] = fzero;
  float m_run[4], l_run[4];
#pragma unroll
  for (int i = 0; i < 4; i++) { m_run[i] = -1e30f; l_run[i] = 0.f; }

  const int ntiles = it + 9;  // covers j <= i0 + 575 >= max valid j = i0+63+512
  for (int t = 0; t < ntiles; t++) {
    const int j0 = t * 64;
    const int relbase = j0 - i0 + 448;  // >= 0 always
    __syncthreads();

    // ---- stage K tile (64 j x 64 d) into B-frag order
#pragma unroll
    for (int cc = 0; cc < 2; cc++) {
      int c = tid + 256 * cc;
      int jl = c >> 3, oct = c & 7;
      int jg = j0 + jl;  // <= 1023 by construction
      short8 val = *reinterpret_cast<const short8*>(kv + ((size_t)jg * BSZ + b) * 2048 + h * 64 + oct * 8);
      int kc = oct >> 2, qd = oct & 3, nc = jl >> 4, nl = jl & 15;
      *reinterpret_cast<short8*>(kt + (((kc * 4 + nc) * 64) + qd * 16 + nl) * 8) = val;
    }
    // ---- stage V tile transposed (frag n-dim = d, k-dim = jl)
#pragma unroll
    for (int cc = 0; cc < 2; cc++) {
      int c = tid + 256 * cc;
      int jl = c >> 3, oct = c & 7;
      int jg = j0 + jl;
      short8 val = *reinterpret_cast<const short8*>(kv + ((size_t)jg * BSZ + b) * 2048 + 1024 + h * 64 + oct * 8);
      int kcj = jl >> 5, qdj = (jl >> 3) & 3, jjj = jl & 7;
#pragma unroll
      for (int e = 0; e < 8; e++) {
        int d = oct * 8 + e;
        int ncd = d >> 4, nld = d & 15;
        vt[(((kcj * 4 + ncd) * 64) + qdj * 16 + nld) * 8 + jjj] = val[e];
      }
    }
    // ---- stage R strip (128 rel x 64 d); clamped rows correspond to masked entries
#pragma unroll
    for (int cc = 0; cc < 4; cc++) {
      int c = tid + 256 * cc;
      int rr = c >> 3, oct = c & 7;
      int rel = relbase + rr;
      if (rel > 1023) rel = 1023;
      short8 val = *reinterpret_cast<const short8*>(r + (size_t)rel * 1024 + h * 64 + oct * 8);
      int kc = oct >> 2, qd = oct & 3, nc = rr >> 4, nl = rr & 15;
      *reinterpret_cast<short8*>(rst + (((kc * 8 + nc) * 64) + qd * 16 + nl) * 8) = val;
    }
    __syncthreads();

    // ---- content scores S[m][jl] for this wave's 16 rows
    f32x4 sc[4];
#pragma unroll
    for (int nc = 0; nc < 4; nc++) {
      sc[nc] = fzero;
#pragma unroll
      for (int kc = 0; kc < 2; kc++) {
        short8 kf = *reinterpret_cast<const short8*>(kt + (((kc * 4 + nc) * 64) + lane) * 8);
        sc[nc] = __builtin_amdgcn_mfma_f32_16x16x32_bf16(qu[kc], kf, sc[nc], 0, 0, 0);
      }
    }
    // ---- position strip pos2[m][rr_w], rr_w in [0,79]; wave w covers rr chunks (3-w)..(7-w)
    f32x4 p2[5];
#pragma unroll
    for (int nc = 0; nc < 5; nc++) {
      p2[nc] = fzero;
      int rchunk = (3 - w) + nc;
#pragma unroll
      for (int kc = 0; kc < 2; kc++) {
        short8 rf = *reinterpret_cast<const short8*>(rst + (((kc * 8 + rchunk) * 64) + lane) * 8);
        p2[nc] = __builtin_amdgcn_mfma_f32_16x16x32_bf16(qvf[kc], rf, p2[nc], 0, 0, 0);
      }
    }
    // spill pos2 (C layout) to per-wave LDS for the row-dependent diagonal gather
#pragma unroll
    for (int nc = 0; nc < 5; nc++)
#pragma unroll
      for (int reg = 0; reg < 4; reg++)
        pos2w[w][(quad * 4 + reg) * 84 + nc * 16 + ml] = p2[nc][reg];

    // ---- assemble S + mask + online softmax
    float pv_[4][4];
    float tmax[4] = {-1e30f, -1e30f, -1e30f, -1e30f};
#pragma unroll
    for (int nc = 0; nc < 4; nc++) {
      int jl = nc * 16 + ml;
#pragma unroll
      for (int reg = 0; reg < 4; reg++) {
        int rowl = quad * 4 + reg;
        int rrw = jl - rowl + 15;  // in [0,78]
        float s = sc[nc][reg] + pos2w[w][rowl * 84 + rrw];
        s *= 0.125f;  // 1/sqrt(64)
        int ig = i0 + w * 16 + rowl;
        int jg = j0 + jl;
        if (jg > ig + PREV) s = -1e30f;
        pv_[nc][reg] = s;
        tmax[reg] = fmaxf(tmax[reg], s);
      }
    }
#pragma unroll
    for (int reg = 0; reg < 4; reg++) {
      float tm = tmax[reg];
#pragma unroll
      for (int off = 1; off < 16; off <<= 1) tm = fmaxf(tm, __shfl_xor(tm, off, 64));
      float mnew = fmaxf(m_run[reg], tm);
      float alpha = __expf(m_run[reg] - mnew);
      float rs = 0.f;
#pragma unroll
      for (int nc = 0; nc < 4; nc++) {
        float p = __expf(pv_[nc][reg] - mnew);
        pv_[nc][reg] = p;
        rs += p;
      }
#pragma unroll
      for (int off = 1; off < 16; off <<= 1) rs += __shfl_xor(rs, off, 64);
      l_run[reg] = l_run[reg] * alpha + rs;
      m_run[reg] = mnew;
#pragma unroll
      for (int nc = 0; nc < 4; nc++) o_acc[nc][reg] *= alpha;
    }

    // ---- P (C layout) -> bf16 A-frag via per-wave LDS transpose
#pragma unroll
    for (int nc = 0; nc < 4; nc++) {
      int jl = nc * 16 + ml;
      int kc = nc >> 1, qdj = (jl >> 3) & 3, jj = ml & 7;
#pragma unroll
      for (int reg = 0; reg < 4; reg++) {
        int rowl = quad * 4 + reg;
        pt[w][(kc * 64 + qdj * 16 + rowl) * 8 + jj] = (short)f2b(pv_[nc][reg]);
      }
    }
    short8 pf[2];
    pf[0] = *reinterpret_cast<const short8*>(pt[w] + (0 * 64 + lane) * 8);
    pf[1] = *reinterpret_cast<const short8*>(pt[w] + (1 * 64 + lane) * 8);

    // ---- PV accumulate: O[m][d] += P[m][jl] V[jl][d]
#pragma unroll
    for (int ncd = 0; ncd < 4; ncd++)
#pragma unroll
      for (int kc = 0; kc < 2; kc++) {
        short8 vf = *reinterpret_cast<const short8*>(vt + (((kc * 4 + ncd) * 64) + lane) * 8);
        o_acc[ncd] = __builtin_amdgcn_mfma_f32_16x16x32_bf16(pf[kc], vf, o_acc[ncd], 0, 0, 0);
      }
  }

  // ---- normalize and write attn_vec
  float inv[4];
#pragma unroll
  for (int reg = 0; reg < 4; reg++) inv[reg] = 1.0f / l_run[reg];
#pragma unroll
  for (int ncd = 0; ncd < 4; ncd++) {
#pragma unroll
    for (int reg = 0; reg < 4; reg++) {
      int rowl = quad * 4 + reg;
      int ig = i0 + w * 16 + rowl;
      av[((size_t)ig * BSZ + b) * 1024 + h * 64 + ncd * 16 + ml] = f2b(o_acc[ncd][reg] * inv[reg]);
    }
  }
}

// ---------------------------------------------------------------------------
extern "C" void kernel_launch(void* const* d_in, const int* in_sizes, int n_in,
                              void* d_out, int out_size, void* d_ws, size_t ws_size,
                              hipStream_t stream) {
  (void)in_sizes; (void)n_in; (void)out_size; (void)ws_size;

  const float* inputs  = (const float*)d_in[0];   // (512,4,1024)
  const float* pos_emb = (const float*)d_in[1];   // (1024,1,1024)
  const float* full_in = (const float*)d_in[2];   // (1024,4,1024)
  const float* u       = (const float*)d_in[3];   // (16,64)
  const float* v       = (const float*)d_in[4];   // (16,64)
  const float* W_kv    = (const float*)d_in[5];   // (1024,2048)
  const float* b_kv    = (const float*)d_in[6];   // (2048,)
  const float* W_q     = (const float*)d_in[7];   // (1024,1024)
  const float* b_q     = (const float*)d_in[8];
  const float* W_pos   = (const float*)d_in[9];   // (1024,1024)
  const float* b_pos   = (const float*)d_in[10];
  const float* W_proj  = (const float*)d_in[11];  // (1024,1024)
  const float* b_proj  = (const float*)d_in[12];
  // d_in[13] = mask (bool) — recomputed analytically (j > i + 512)
  float* out = (float*)d_out;

  char* ws = (char*)d_ws;
  u16* kv = (u16*)(ws);                                            // 16 MB
  u16* qq = (u16*)(ws + (16u << 20));                              // 4 MB
  u16* rr = (u16*)(ws + (16u << 20) + (4u << 20));                 // 2 MB
  u16* av = (u16*)(ws + (16u << 20) + (4u << 20) + (2u << 20));    // 4 MB

  hipLaunchKernelGGL((gemm_any<float, u16>), dim3(16, 32), dim3(256), 0, stream,
                     full_in, W_kv, b_kv, kv, 4096, 2048, 1024);
  hipLaunchKernelGGL((gemm_any<float, u16>), dim3(8, 16), dim3(256), 0, stream,
                     inputs, W_q, b_q, qq, 2048, 1024, 1024);
  hipLaunchKernelGGL((gemm_any<float, u16>), dim3(8, 8), dim3(256), 0, stream,
                     pos_emb, W_pos, b_pos, rr, 1024, 1024, 1024);
  hipLaunchKernelGGL(flash_xl, dim3(8, 4, 16), dim3(256), 0, stream,
                     qq, kv, rr, u, v, av);
  hipLaunchKernelGGL((gemm_any<u16, float>), dim3(8, 16), dim3(256), 0, stream,
                     av, W_proj, b_proj, out, 2048, 1024, 1024);
}

// Round 5
// 331.083 us; speedup vs baseline: 6.9565x; 1.3578x over previous
//
#include <hip/hip_runtime.h>

// AttentionXL (TransformerXL relative attention), MI355X gfx950.
// fp32 I/O. Pipeline: bf16 precompute (convert + weight transpose) ->
// 4x bf16 B^T-GEMM (MFMA, fp32 accum) -> fused MFMA flash-XL.
// This round: GEMM staging rewrite (kill LDS bank conflicts + fp32 staging).

typedef unsigned short u16;
typedef short short8 __attribute__((ext_vector_type(8)));
typedef float f32x4 __attribute__((ext_vector_type(4)));

#define CUR 512
#define FULLS 1024
#define BSZ 4
#define NH 16
#define DH 64
#define PREV 512

__device__ __forceinline__ float b2f(u16 u) {
  union { unsigned int i; float f; } x; x.i = ((unsigned int)u) << 16; return x.f;
}
__device__ __forceinline__ u16 f2b(float f) {
  union { float f; unsigned int i; } x; x.f = f;
  unsigned int u = x.i;
  return (u16)((u + 0x7fffu + ((u >> 16) & 1u)) >> 16);
}
__device__ __forceinline__ void storeC(u16* C, size_t idx, float v) { C[idx] = f2b(v); }
__device__ __forceinline__ void storeC(float* C, size_t idx, float v) { C[idx] = v; }

// ---------------------------------------------------------------------------
// fp32 -> bf16 flat convert. n must be divisible by 2048; grid = n/2048.
// ---------------------------------------------------------------------------
__global__ __launch_bounds__(256)
void convert_bf16(const float* __restrict__ src, u16* __restrict__ dst) {
  size_t i = ((size_t)blockIdx.x * 256 + threadIdx.x) * 8;
  const f32x4* p = reinterpret_cast<const f32x4*>(src + i);
  f32x4 a = p[0], b = p[1];
  short8 r;
#pragma unroll
  for (int e = 0; e < 4; e++) { r[e] = (short)f2b(a[e]); r[e + 4] = (short)f2b(b[e]); }
  *reinterpret_cast<short8*>(dst + i) = r;
}

// ---------------------------------------------------------------------------
// fp32 W[K x N] -> bf16 WT[N x K]. 64x64 tiles via LDS (pad 66).
// grid = (N/64, K/64), block = 256.
// ---------------------------------------------------------------------------
__global__ __launch_bounds__(256)
void transpose_bf16(const float* __restrict__ W, u16* __restrict__ WT, int K, int N) {
  __shared__ u16 ld[64 * 66];
  const int tid = threadIdx.x;
  const int n0 = blockIdx.x * 64, k0 = blockIdx.y * 64;
#pragma unroll
  for (int rep = 0; rep < 16; rep++) {
    int idx = tid + 256 * rep;
    int kk = idx >> 6, nn = idx & 63;
    ld[kk * 66 + nn] = f2b(W[(size_t)(k0 + kk) * N + n0 + nn]);
  }
  __syncthreads();
#pragma unroll
  for (int rep = 0; rep < 16; rep++) {
    int idx = tid + 256 * rep;
    int nn = idx >> 6, kk = idx & 63;
    WT[(size_t)(n0 + nn) * K + k0 + kk] = ld[kk * 66 + nn];
  }
}

// ---------------------------------------------------------------------------
// GEMM (B^T form): C[M,N] = A[M,K] @ BT[N,K]^T + bias[N].
// A, BT bf16 k-contiguous; C fp32 or bf16. 128x128 tile, BK=64, 4 waves (2x2).
// All LDS traffic is b128 (conflict-free); no cvt in the K-loop.
// ---------------------------------------------------------------------------
template <typename OT>
__global__ __launch_bounds__(256, 2)
void gemm_bt(const u16* __restrict__ A, const u16* __restrict__ BT,
             const float* __restrict__ bias, OT* __restrict__ C,
             int M, int N, int K)
{
  __shared__ __align__(16) short at[8192];  // [(mc*2+kc)][qd*16+mll][8]
  __shared__ __align__(16) short bt[8192];  // [(nc*2+kc)][qd*16+nl][8]

  const int tid = threadIdx.x;
  const int lane = tid & 63, w = tid >> 6;
  const int wr = w >> 1, wc = w & 1;
  const int quad = lane >> 4, ml = lane & 15;
  const int row0 = blockIdx.y * 128, col0 = blockIdx.x * 128;

  f32x4 acc[4][4];
  const f32x4 fzero = {0.f, 0.f, 0.f, 0.f};
#pragma unroll
  for (int i = 0; i < 4; i++)
#pragma unroll
    for (int j = 0; j < 4; j++) acc[i][j] = fzero;

  for (int k0 = 0; k0 < K; k0 += 64) {
    __syncthreads();
#pragma unroll
    for (int cc = 0; cc < 4; cc++) {
      int c = tid + 256 * cc;
      int m = c >> 3, oct = c & 7;
      short8 val = *reinterpret_cast<const short8*>(A + (size_t)(row0 + m) * K + k0 + oct * 8);
      int mc = m >> 4, mll = m & 15, kc = oct >> 2, qd = oct & 3;
      *reinterpret_cast<short8*>(at + (((mc * 2 + kc) * 64) + qd * 16 + mll) * 8) = val;
    }
#pragma unroll
    for (int cc = 0; cc < 4; cc++) {
      int c = tid + 256 * cc;
      int n = c >> 3, oct = c & 7;
      short8 val = *reinterpret_cast<const short8*>(BT + (size_t)(col0 + n) * K + k0 + oct * 8);
      int nc = n >> 4, nl = n & 15, kc = oct >> 2, qd = oct & 3;
      *reinterpret_cast<short8*>(bt + (((nc * 2 + kc) * 64) + qd * 16 + nl) * 8) = val;
    }
    __syncthreads();

    short8 af[4][2], bf[4][2];
#pragma unroll
    for (int mc = 0; mc < 4; mc++)
#pragma unroll
      for (int kc = 0; kc < 2; kc++)
        af[mc][kc] = *reinterpret_cast<const short8*>(at + ((((wr * 4 + mc) * 2 + kc) * 64) + lane) * 8);
#pragma unroll
    for (int nc = 0; nc < 4; nc++)
#pragma unroll
      for (int kc = 0; kc < 2; kc++)
        bf[nc][kc] = *reinterpret_cast<const short8*>(bt + ((((wc * 4 + nc) * 2 + kc) * 64) + lane) * 8);

#pragma unroll
    for (int mc = 0; mc < 4; mc++)
#pragma unroll
      for (int nc = 0; nc < 4; nc++)
#pragma unroll
        for (int kc = 0; kc < 2; kc++)
          acc[mc][nc] = __builtin_amdgcn_mfma_f32_16x16x32_bf16(af[mc][kc], bf[nc][kc], acc[mc][nc], 0, 0, 0);
  }

#pragma unroll
  for (int nc = 0; nc < 4; nc++) {
    int col = col0 + wc * 64 + nc * 16 + ml;
    float bv = bias[col];
#pragma unroll
    for (int mc = 0; mc < 4; mc++) {
#pragma unroll
      for (int reg = 0; reg < 4; reg++) {
        int row = row0 + wr * 64 + mc * 16 + quad * 4 + reg;
        storeC(C, (size_t)row * N + col, acc[mc][nc][reg] + bv);
      }
    }
  }
}

// ---------------------------------------------------------------------------
// Fused MFMA flash attention with TransformerXL relative position (unchanged).
// ---------------------------------------------------------------------------
__global__ __launch_bounds__(256, 2)
void flash_xl(const u16* __restrict__ q, const u16* __restrict__ kv,
              const u16* __restrict__ r, const float* __restrict__ u,
              const float* __restrict__ v, u16* __restrict__ av)
{
  __shared__ __align__(16) short kt[4096];
  __shared__ __align__(16) short vt[4096];
  __shared__ __align__(16) short rst[8192];
  __shared__ float pos2w[4][16 * 84];
  __shared__ __align__(16) short pt[4][1024];

  const int tid = threadIdx.x, lane = tid & 63, w = tid >> 6;
  const int quad = lane >> 4, ml = lane & 15;
  const int it = blockIdx.x, b = blockIdx.y, h = blockIdx.z;
  const int i0 = it * 64;

  short8 qu[2], qvf[2];
  {
    int ig = i0 + w * 16 + ml;
#pragma unroll
    for (int kc = 0; kc < 2; kc++) {
      int dbase = kc * 32 + quad * 8;
      short8 qq = *reinterpret_cast<const short8*>(q + ((size_t)ig * BSZ + b) * 1024 + h * 64 + dbase);
      const f32x4* up = reinterpret_cast<const f32x4*>(u + h * 64 + dbase);
      const f32x4* vp = reinterpret_cast<const f32x4*>(v + h * 64 + dbase);
      f32x4 u0 = up[0], u1 = up[1], v0 = vp[0], v1 = vp[1];
#pragma unroll
      for (int e = 0; e < 8; e++) {
        float qf = b2f((u16)qq[e]);
        float uu = (e < 4) ? u0[e] : u1[e - 4];
        float vv = (e < 4) ? v0[e] : v1[e - 4];
        qu[kc][e]  = (short)f2b(qf + uu);
        qvf[kc][e] = (short)f2b(qf + vv);
      }
    }
  }

  const f32x4 fzero = {0.f, 0.f, 0.f, 0.f};
  f32x4 o_acc[4];
#pragma unroll
  for (int i = 0; i < 4; i++) o_acc[i] = fzero;
  float m_run[4], l_run[4];
#pragma unroll
  for (int i = 0; i < 4; i++) { m_run[i] = -1e30f; l_run[i] = 0.f; }

  const int ntiles = it + 9;
  for (int t = 0; t < ntiles; t++) {
    const int j0 = t * 64;
    const int relbase = j0 - i0 + 448;
    __syncthreads();

#pragma unroll
    for (int cc = 0; cc < 2; cc++) {
      int c = tid + 256 * cc;
      int jl = c >> 3, oct = c & 7;
      int jg = j0 + jl;
      short8 val = *reinterpret_cast<const short8*>(kv + ((size_t)jg * BSZ + b) * 2048 + h * 64 + oct * 8);
      int kc = oct >> 2, qd = oct & 3, nc = jl >> 4, nl = jl & 15;
      *reinterpret_cast<short8*>(kt + (((kc * 4 + nc) * 64) + qd * 16 + nl) * 8) = val;
    }
#pragma unroll
    for (int cc = 0; cc < 2; cc++) {
      int c = tid + 256 * cc;
      int jl = c >> 3, oct = c & 7;
      int jg = j0 + jl;
      short8 val = *reinterpret_cast<const short8*>(kv + ((size_t)jg * BSZ + b) * 2048 + 1024 + h * 64 + oct * 8);
      int kcj = jl >> 5, qdj = (jl >> 3) & 3, jjj = jl & 7;
#pragma unroll
      for (int e = 0; e < 8; e++) {
        int d = oct * 8 + e;
        int ncd = d >> 4, nld = d & 15;
        vt[(((kcj * 4 + ncd) * 64) + qdj * 16 + nld) * 8 + jjj] = val[e];
      }
    }
#pragma unroll
    for (int cc = 0; cc < 4; cc++) {
      int c = tid + 256 * cc;
      int rr = c >> 3, oct = c & 7;
      int rel = relbase + rr;
      if (rel > 1023) rel = 1023;
      short8 val = *reinterpret_cast<const short8*>(r + (size_t)rel * 1024 + h * 64 + oct * 8);
      int kc = oct >> 2, qd = oct & 3, nc = rr >> 4, nl = rr & 15;
      *reinterpret_cast<short8*>(rst + (((kc * 8 + nc) * 64) + qd * 16 + nl) * 8) = val;
    }
    __syncthreads();

    f32x4 sc[4];
#pragma unroll
    for (int nc = 0; nc < 4; nc++) {
      sc[nc] = fzero;
#pragma unroll
      for (int kc = 0; kc < 2; kc++) {
        short8 kf = *reinterpret_cast<const short8*>(kt + (((kc * 4 + nc) * 64) + lane) * 8);
        sc[nc] = __builtin_amdgcn_mfma_f32_16x16x32_bf16(qu[kc], kf, sc[nc], 0, 0, 0);
      }
    }
    f32x4 p2[5];
#pragma unroll
    for (int nc = 0; nc < 5; nc++) {
      p2[nc] = fzero;
      int rchunk = (3 - w) + nc;
#pragma unroll
      for (int kc = 0; kc < 2; kc++) {
        short8 rf = *reinterpret_cast<const short8*>(rst + (((kc * 8 + rchunk) * 64) + lane) * 8);
        p2[nc] = __builtin_amdgcn_mfma_f32_16x16x32_bf16(qvf[kc], rf, p2[nc], 0, 0, 0);
      }
    }
#pragma unroll
    for (int nc = 0; nc < 5; nc++)
#pragma unroll
      for (int reg = 0; reg < 4; reg++)
        pos2w[w][(quad * 4 + reg) * 84 + nc * 16 + ml] = p2[nc][reg];

    float pv_[4][4];
    float tmax[4] = {-1e30f, -1e30f, -1e30f, -1e30f};
#pragma unroll
    for (int nc = 0; nc < 4; nc++) {
      int jl = nc * 16 + ml;
#pragma unroll
      for (int reg = 0; reg < 4; reg++) {
        int rowl = quad * 4 + reg;
        int rrw = jl - rowl + 15;
        float s = sc[nc][reg] + pos2w[w][rowl * 84 + rrw];
        s *= 0.125f;
        int ig = i0 + w * 16 + rowl;
        int jg = j0 + jl;
        if (jg > ig + PREV) s = -1e30f;
        pv_[nc][reg] = s;
        tmax[reg] = fmaxf(tmax[reg], s);
      }
    }
#pragma unroll
    for (int reg = 0; reg < 4; reg++) {
      float tm = tmax[reg];
#pragma unroll
      for (int off = 1; off < 16; off <<= 1) tm = fmaxf(tm, __shfl_xor(tm, off, 64));
      float mnew = fmaxf(m_run[reg], tm);
      float alpha = __expf(m_run[reg] - mnew);
      float rs = 0.f;
#pragma unroll
      for (int nc = 0; nc < 4; nc++) {
        float p = __expf(pv_[nc][reg] - mnew);
        pv_[nc][reg] = p;
        rs += p;
      }
#pragma unroll
      for (int off = 1; off < 16; off <<= 1) rs += __shfl_xor(rs, off, 64);
      l_run[reg] = l_run[reg] * alpha + rs;
      m_run[reg] = mnew;
#pragma unroll
      for (int nc = 0; nc < 4; nc++) o_acc[nc][reg] *= alpha;
    }

#pragma unroll
    for (int nc = 0; nc < 4; nc++) {
      int jl = nc * 16 + ml;
      int kc = nc >> 1, qdj = (jl >> 3) & 3, jj = ml & 7;
#pragma unroll
      for (int reg = 0; reg < 4; reg++) {
        int rowl = quad * 4 + reg;
        pt[w][(kc * 64 + qdj * 16 + rowl) * 8 + jj] = (short)f2b(pv_[nc][reg]);
      }
    }
    short8 pf[2];
    pf[0] = *reinterpret_cast<const short8*>(pt[w] + (0 * 64 + lane) * 8);
    pf[1] = *reinterpret_cast<const short8*>(pt[w] + (1 * 64 + lane) * 8);

#pragma unroll
    for (int ncd = 0; ncd < 4; ncd++)
#pragma unroll
      for (int kc = 0; kc < 2; kc++) {
        short8 vf = *reinterpret_cast<const short8*>(vt + (((kc * 4 + ncd) * 64) + lane) * 8);
        o_acc[ncd] = __builtin_amdgcn_mfma_f32_16x16x32_bf16(pf[kc], vf, o_acc[ncd], 0, 0, 0);
      }
  }

  float inv[4];
#pragma unroll
  for (int reg = 0; reg < 4; reg++) inv[reg] = 1.0f / l_run[reg];
#pragma unroll
  for (int ncd = 0; ncd < 4; ncd++) {
#pragma unroll
    for (int reg = 0; reg < 4; reg++) {
      int rowl = quad * 4 + reg;
      int ig = i0 + w * 16 + rowl;
      av[((size_t)ig * BSZ + b) * 1024 + h * 64 + ncd * 16 + ml] = f2b(o_acc[ncd][reg] * inv[reg]);
    }
  }
}

// ---------------------------------------------------------------------------
extern "C" void kernel_launch(void* const* d_in, const int* in_sizes, int n_in,
                              void* d_out, int out_size, void* d_ws, size_t ws_size,
                              hipStream_t stream) {
  (void)in_sizes; (void)n_in; (void)out_size; (void)ws_size;

  const float* inputs  = (const float*)d_in[0];   // (512,4,1024)
  const float* pos_emb = (const float*)d_in[1];   // (1024,1,1024)
  const float* full_in = (const float*)d_in[2];   // (1024,4,1024)
  const float* u       = (const float*)d_in[3];   // (16,64)
  const float* v       = (const float*)d_in[4];   // (16,64)
  const float* W_kv    = (const float*)d_in[5];   // (1024,2048)
  const float* b_kv    = (const float*)d_in[6];   // (2048,)
  const float* W_q     = (const float*)d_in[7];   // (1024,1024)
  const float* b_q     = (const float*)d_in[8];
  const float* W_pos   = (const float*)d_in[9];   // (1024,1024)
  const float* b_pos   = (const float*)d_in[10];
  const float* W_proj  = (const float*)d_in[11];  // (1024,1024)
  const float* b_proj  = (const float*)d_in[12];
  // d_in[13] = mask (bool) — recomputed analytically (j > i + 512)
  float* out = (float*)d_out;

  char* ws = (char*)d_ws;
  u16* kv    = (u16*)(ws);                  // 16 MB: 4096x2048
  u16* qq    = (u16*)(ws + (16u << 20));    //  4 MB: 2048x1024
  u16* rr    = (u16*)(ws + (20u << 20));    //  2 MB: 1024x1024
  u16* av    = (u16*)(ws + (22u << 20));    //  4 MB: 2048x1024
  u16* fibf  = (u16*)(ws + (26u << 20));    //  8 MB: 4096x1024
  u16* inbf  = (u16*)(ws + (34u << 20));    //  4 MB: 2048x1024
  u16* pebf  = (u16*)(ws + (38u << 20));    //  2 MB: 1024x1024
  u16* WkvT  = (u16*)(ws + (40u << 20));    //  4 MB: 2048x1024
  u16* WqT   = (u16*)(ws + (44u << 20));    //  2 MB: 1024x1024
  u16* WposT = (u16*)(ws + (46u << 20));    //  2 MB: 1024x1024
  u16* WprojT= (u16*)(ws + (48u << 20));    //  2 MB: 1024x1024

  // --- precompute: bf16 activations + transposed bf16 weights
  hipLaunchKernelGGL(convert_bf16, dim3(2048), dim3(256), 0, stream, full_in, fibf);
  hipLaunchKernelGGL(convert_bf16, dim3(1024), dim3(256), 0, stream, inputs, inbf);
  hipLaunchKernelGGL(convert_bf16, dim3(512),  dim3(256), 0, stream, pos_emb, pebf);
  hipLaunchKernelGGL(transpose_bf16, dim3(32, 16), dim3(256), 0, stream, W_kv, WkvT, 1024, 2048);
  hipLaunchKernelGGL(transpose_bf16, dim3(16, 16), dim3(256), 0, stream, W_q, WqT, 1024, 1024);
  hipLaunchKernelGGL(transpose_bf16, dim3(16, 16), dim3(256), 0, stream, W_pos, WposT, 1024, 1024);
  hipLaunchKernelGGL(transpose_bf16, dim3(16, 16), dim3(256), 0, stream, W_proj, WprojT, 1024, 1024);

  // --- GEMMs (B^T form)
  hipLaunchKernelGGL((gemm_bt<u16>), dim3(16, 32), dim3(256), 0, stream,
                     fibf, WkvT, b_kv, kv, 4096, 2048, 1024);
  hipLaunchKernelGGL((gemm_bt<u16>), dim3(8, 16), dim3(256), 0, stream,
                     inbf, WqT, b_q, qq, 2048, 1024, 1024);
  hipLaunchKernelGGL((gemm_bt<u16>), dim3(8, 8), dim3(256), 0, stream,
                     pebf, WposT, b_pos, rr, 1024, 1024, 1024);
  // --- fused attention
  hipLaunchKernelGGL(flash_xl, dim3(8, 4, 16), dim3(256), 0, stream,
                     qq, kv, rr, u, v, av);
  // --- output projection
  hipLaunchKernelGGL((gemm_bt<float>), dim3(8, 16), dim3(256), 0, stream,
                     av, WprojT, b_proj, out, 2048, 1024, 1024);
}